// Round 1
// baseline (1889.533 us; speedup 1.0000x reference)
//
#include <hip/hip_runtime.h>

#define D 256
#define CHUNK 8
#define NCHUNK 32   // 256/8
#define SPB 8       // samples per block (2 per wave, 4 waves)

__device__ __forceinline__ float wsum(float v) {
    #pragma unroll
    for (int off = 32; off > 0; off >>= 1) v += __shfl_xor(v, off, 64);
    return v;
}
__device__ __forceinline__ float wmax(float v) {
    #pragma unroll
    for (int off = 32; off > 0; off >>= 1) v = fmaxf(v, __shfl_xor(v, off, 64));
    return v;
}
__device__ __forceinline__ void ld4(float* d, const float* s) {
    float4 t = *(const float4*)s; d[0]=t.x; d[1]=t.y; d[2]=t.z; d[3]=t.w;
}
__device__ __forceinline__ void st4s(float* s, const float* d) {
    float4 t; t.x=d[0]; t.y=d[1]; t.z=d[2]; t.w=d[3]; *(float4*)s = t;
}

__global__ __launch_bounds__(256) void divfree_kernel(
    const float* __restrict__ x,
    const float* __restrict__ w_in,
    const float* __restrict__ b_in,
    const float* __restrict__ w_hid,
    const float* __restrict__ b_hid,
    const float* __restrict__ w_out,
    const float* __restrict__ b_out,
    float* __restrict__ out,
    int N)
{
    // A-state: 8 samples x 4 rows (primal + 3 tangents) x 256. Rows are
    // wave-private (wave w owns rows 8w..8w+7) -> no barriers needed on sA.
    __shared__ float sA[32 * D];               // 32 KB
    __shared__ float sW[2][CHUNK * D];         // 2 x 8 KB double-buffered W slab

    const int tid  = threadIdx.x;
    const int wave = tid >> 6;
    const int lane = tid & 63;
    const int col0 = lane << 2;                // 4 cols per lane
    const int rowbase = wave << 3;             // 8 rows per wave
    const int sample0 = blockIdx.x * SPB + (wave << 1);

    // ---------------- input layer (K=3) ----------------
    float wi[3][4], bi[4];
    ld4(wi[0], w_in + 0*D + col0);
    ld4(wi[1], w_in + 1*D + col0);
    ld4(wi[2], w_in + 2*D + col0);
    ld4(bi,    b_in + col0);
    #pragma unroll
    for (int g = 0; g < 2; ++g) {
        int s = sample0 + g; if (s >= N) s = N - 1;
        float x0 = x[s*3+0], x1 = x[s*3+1], x2 = x[s*3+2];
        float hv[4], d0[4], d1[4], d2[4];
        #pragma unroll
        for (int i = 0; i < 4; ++i) {
            float pre = x0*wi[0][i] + x1*wi[1][i] + x2*wi[2][i] + bi[i];
            float sig = 1.f / (1.f + __expf(-pre));
            float sp  = sig * (1.f + pre * (1.f - sig)); // silu'
            hv[i] = pre * sig;                            // silu
            d0[i] = sp * wi[0][i];
            d1[i] = sp * wi[1][i];
            d2[i] = sp * wi[2][i];
        }
        int rb = rowbase + 4*g;
        st4s(&sA[(rb+0)*D + col0], hv);
        st4s(&sA[(rb+1)*D + col0], d0);
        st4s(&sA[(rb+2)*D + col0], d1);
        st4s(&sA[(rb+3)*D + col0], d2);
    }

    // ---------------- 3 hidden GEMMs + output GEMM ----------------
    for (int l = 0; l < 4; ++l) {
        const float* Wl = (l < 3) ? (w_hid + l*D*D) : w_out;
        const float* bl = (l < 3) ? (b_hid + l*D)   : b_out;

        float acc[8][4];
        #pragma unroll
        for (int r = 0; r < 8; ++r)
            #pragma unroll
            for (int c = 0; c < 4; ++c) acc[r][c] = 0.f;

        // prologue: stage chunk 0 (W rows 0..7, contiguous 8 KB)
        {
            float4 p0 = *(const float4*)(Wl + 4*tid);
            float4 p1 = *(const float4*)(Wl + 1024 + 4*tid);
            *(float4*)(&sW[0][4*tid])        = p0;
            *(float4*)(&sW[0][1024 + 4*tid]) = p1;
        }
        __syncthreads();

        int p = 0;
        for (int ch = 0; ch < NCHUNK; ++ch) {
            float4 n0, n1;
            const bool more = (ch + 1 < NCHUNK);
            if (more) {                       // prefetch next slab while computing
                const float* src = Wl + (ch+1)*CHUNK*D;
                n0 = *(const float4*)(src + 4*tid);
                n1 = *(const float4*)(src + 1024 + 4*tid);
            }
            const float* wb = sW[p];
            const int k0 = ch * CHUNK;
            #pragma unroll
            for (int kb = 0; kb < 2; ++kb) {
                const int kloc = kb * 4;
                float wf[4][4];               // [k][col]
                #pragma unroll
                for (int kk = 0; kk < 4; ++kk)
                    ld4(wf[kk], wb + (kloc+kk)*D + col0);
                #pragma unroll
                for (int r = 0; r < 8; ++r) {
                    float av[4];              // full-wave broadcast read
                    ld4(av, &sA[(rowbase + r)*D + k0 + kloc]);
                    #pragma unroll
                    for (int c = 0; c < 4; ++c)
                        acc[r][c] = fmaf(av[3], wf[3][c],
                                    fmaf(av[2], wf[2][c],
                                    fmaf(av[1], wf[1][c],
                                    fmaf(av[0], wf[0][c], acc[r][c]))));
                }
            }
            if (more) {
                *(float4*)(&sW[p^1][4*tid])        = n0;
                *(float4*)(&sW[p^1][1024 + 4*tid]) = n1;
            }
            __syncthreads();
            p ^= 1;
        }

        float bv[4]; ld4(bv, bl + col0);
        if (l < 3) {
            // bias + silu on primal row, silu'(pre)*t_k on tangent rows
            #pragma unroll
            for (int g = 0; g < 2; ++g) {
                float hv[4], t1[4], t2[4], t3[4];
                #pragma unroll
                for (int i = 0; i < 4; ++i) {
                    float pre = acc[4*g][i] + bv[i];
                    float sig = 1.f / (1.f + __expf(-pre));
                    float sp  = sig * (1.f + pre * (1.f - sig));
                    hv[i] = pre * sig;
                    t1[i] = sp * acc[4*g+1][i];
                    t2[i] = sp * acc[4*g+2][i];
                    t3[i] = sp * acc[4*g+3][i];
                }
                int rb = rowbase + 4*g;
                st4s(&sA[(rb+0)*D + col0], hv);
                st4s(&sA[(rb+1)*D + col0], t1);
                st4s(&sA[(rb+2)*D + col0], t2);
                st4s(&sA[(rb+3)*D + col0], t3);
            }
        } else {
            // epilogue: lane m holds mixture m's (logit, tri[3]) + tangents
            #pragma unroll
            for (int g = 0; g < 2; ++g) {
                float sm  = acc[4*g][0] + bv[0];
                float oa0 = acc[4*g][1] + bv[1];
                float oa1 = acc[4*g][2] + bv[2];
                float oa2 = acc[4*g][3] + bv[3];
                float ds0 = acc[4*g+1][0], ds1 = acc[4*g+2][0], ds2 = acc[4*g+3][0];
                float mx = wmax(sm);
                float e  = __expf(sm - mx);
                float Z  = wsum(e);
                float T0 = wsum(e * ds0) / Z;
                float T1 = wsum(e * ds1) / Z;
                float T2 = wsum(e * ds2) / Z;
                // u0 = G[0][1] + G[1][2]; u1 = -G[0][0] + G[2][2]; u2 = -G[1][0] - G[2][1]
                float g0 =  (ds1 - T1)*oa0 + acc[4*g+2][1]
                         +  (ds2 - T2)*oa1 + acc[4*g+3][2];
                float g1 = -((ds0 - T0)*oa0 + acc[4*g+1][1])
                         +  (ds2 - T2)*oa2 + acc[4*g+3][3];
                float g2 = -((ds0 - T0)*oa1 + acc[4*g+1][2])
                         - ((ds1 - T1)*oa2 + acc[4*g+2][3]);
                float u0 = wsum(e * g0) / Z;
                float u1 = wsum(e * g1) / Z;
                float u2 = wsum(e * g2) / Z;
                int s = sample0 + g;
                if (lane == 0 && s < N) {
                    out[s*3+0] = u0;
                    out[s*3+1] = u1;
                    out[s*3+2] = u2;
                }
            }
        }
    }
}

extern "C" void kernel_launch(void* const* d_in, const int* in_sizes, int n_in,
                              void* d_out, int out_size, void* d_ws, size_t ws_size,
                              hipStream_t stream) {
    const float* x     = (const float*)d_in[0];
    const float* w_in  = (const float*)d_in[1];
    const float* b_in  = (const float*)d_in[2];
    const float* w_hid = (const float*)d_in[3];
    const float* b_hid = (const float*)d_in[4];
    const float* w_out = (const float*)d_in[5];
    const float* b_out = (const float*)d_in[6];
    float* out = (float*)d_out;
    const int N = in_sizes[0] / 3;
    const int blocks = (N + SPB - 1) / SPB;
    divfree_kernel<<<blocks, 256, 0, stream>>>(x, w_in, b_in, w_hid, b_hid,
                                               w_out, b_out, out, N);
}

// Round 2
// 758.091 us; speedup vs baseline: 2.4925x; 2.4925x over previous
//
#include <hip/hip_runtime.h>
#include <stdint.h>

#define THREADS 256
#define SPB 16                 // samples per block -> 64 A-rows (4 per sample)
#define CHUNK_WORDS 8192       // one K=32 chunk of packed W: 8 granules x 256 cols x 4 words
#define LAYER_WORDS 65536      // 8 chunks per 256x256 layer
#define SA_WORDS 16384         // 64 rows x 256 k packed words (64 KB)
#define SB_BASE 16384
#define SB_WORDS 8192          // one 32 KB W chunk buffer

typedef __bf16 bf16x8 __attribute__((ext_vector_type(8)));
typedef float f32x16 __attribute__((ext_vector_type(16)));

union Frag { uint32_t u[4]; bf16x8 v; };

__device__ __forceinline__ uint32_t f2bf(float f) {    // RNE bf16 bits (finite inputs)
    uint32_t u = __float_as_uint(f);
    return (u + 0x7fffu + ((u >> 16) & 1u)) >> 16;
}
__device__ __forceinline__ uint32_t pack_hilo(float f) {
    uint32_t hb = f2bf(f);
    float hf = __uint_as_float(hb << 16);
    uint32_t lb = f2bf(f - hf);
    return hb | (lb << 16);
}
// A-state LDS word address: granule slab kg (=k>>2) of 64 rows x 16B, XOR-swizzled
// so epilogue writes (fixed m, varying kg) and frag reads (fixed kg, varying m)
// are both conflict-free.
__device__ __forceinline__ int awords(int m, int k) {
    int kg = k >> 2;
    return (kg << 8) + (((m ^ (kg & 7))) << 2) + (k & 3);
}

__device__ __forceinline__ float wsum(float v) {
    #pragma unroll
    for (int off = 32; off > 0; off >>= 1) v += __shfl_xor(v, off, 64);
    return v;
}
__device__ __forceinline__ float wmax(float v) {
    #pragma unroll
    for (int off = 32; off > 0; off >>= 1) v = fmaxf(v, __shfl_xor(v, off, 64));
    return v;
}

// ---- pre-kernel: pack W (hi|lo bf16) into the exact LDS chunk image ----
// ws word idx = l*65536 + kt*8192 + kkg*1024 + n*4 + w   (k = kt*32 + kkg*4 + w)
__global__ __launch_bounds__(256) void pack_w(const float* __restrict__ w_hid,
                                              const float* __restrict__ w_out,
                                              uint32_t* __restrict__ Wp) {
    int idx = blockIdx.x * 256 + threadIdx.x;      // 0..262143
    int l   = idx >> 16;
    int r   = idx & 65535;
    int kt  = r >> 13;
    int r2  = r & 8191;
    int kkg = r2 >> 10;
    int r3  = r2 & 1023;
    int n   = r3 >> 2;
    int w   = r3 & 3;
    int k   = kt * 32 + kkg * 4 + w;
    float v = (l < 3) ? w_hid[l * 65536 + k * 256 + n] : w_out[k * 256 + n];
    Wp[idx] = pack_hilo(v);
}

__global__ __launch_bounds__(THREADS) void divfree_mfma(
    const float* __restrict__ x,
    const uint32_t* __restrict__ Wp,
    const float* __restrict__ w_in,
    const float* __restrict__ b_in,
    const float* __restrict__ b_hid,
    const float* __restrict__ b_out,
    float* __restrict__ out)
{
    __shared__ uint32_t lds[32768];                // 128 KB: sA 64KB + 2x32KB W bufs
    const int tid  = threadIdx.x;
    const int wave = tid >> 6, lane = tid & 63;
    const int l5 = lane >> 5, ln = lane & 31;
    const int s0 = blockIdx.x * SPB;

    auto stage = [&](const uint32_t* src, int bufbase) {
        const uint32_t* g = src + wave * 2048 + lane * 4;
        #pragma unroll
        for (int i = 0; i < 8; ++i) {
            __builtin_amdgcn_global_load_lds(
                (const __attribute__((address_space(1))) uint32_t*)(g + i * 256),
                (__attribute__((address_space(3))) uint32_t*)(&lds[bufbase + wave * 2048 + i * 256]),
                16, 0, 0);
        }
    };

    // async-stage layer0 chunk0 while computing the input layer
    stage(Wp, SB_BASE);

    { // ---- input layer: A rows = [silu(pre), silu'(pre)*w_in[k,:]] ----
        int s  = tid >> 4;                 // 0..15
        int kb = (tid & 15) << 4;          // 16 k's per thread
        int sg = s0 + s;
        float x0 = x[sg * 3 + 0], x1 = x[sg * 3 + 1], x2 = x[sg * 3 + 2];
        #pragma unroll
        for (int i = 0; i < 16; i += 4) {
            int k = kb + i;
            float4 w0 = *(const float4*)&w_in[k];
            float4 w1 = *(const float4*)&w_in[256 + k];
            float4 w2 = *(const float4*)&w_in[512 + k];
            float4 bb = *(const float4*)&b_in[k];
            float W0[4] = {w0.x, w0.y, w0.z, w0.w};
            float W1[4] = {w1.x, w1.y, w1.z, w1.w};
            float W2[4] = {w2.x, w2.y, w2.z, w2.w};
            float BB[4] = {bb.x, bb.y, bb.z, bb.w};
            #pragma unroll
            for (int e = 0; e < 4; ++e) {
                float pre = x0 * W0[e] + x1 * W1[e] + x2 * W2[e] + BB[e];
                float sig = 1.f / (1.f + __expf(-pre));
                float sp  = sig * (1.f + pre * (1.f - sig));
                lds[awords(4 * s + 0, k + e)] = pack_hilo(pre * sig);
                lds[awords(4 * s + 1, k + e)] = pack_hilo(sp * W0[e]);
                lds[awords(4 * s + 2, k + e)] = pack_hilo(sp * W1[e]);
                lds[awords(4 * s + 3, k + e)] = pack_hilo(sp * W2[e]);
            }
        }
    }
    __syncthreads();

    #pragma unroll 1
    for (int l = 0; l < 4; ++l) {
        const uint32_t* Wl = Wp + l * LAYER_WORDS;
        f32x16 acc[2][2];
        #pragma unroll
        for (int a = 0; a < 2; ++a)
            #pragma unroll
            for (int b = 0; b < 2; ++b) acc[a][b] = (f32x16)0.0f;

        int p = 0;
        #pragma unroll 1
        for (int c = 0; c < 8; ++c) {
            if (c < 7)       stage(Wl + (c + 1) * CHUNK_WORDS, SB_BASE + (p ^ 1) * SB_WORDS);
            else if (l < 3)  stage(Wp + (l + 1) * LAYER_WORDS, SB_BASE + (p ^ 1) * SB_WORDS);

            const int bb0 = SB_BASE + p * SB_WORDS;
            #pragma unroll
            for (int tc = 0; tc < 2; ++tc) {
                const int t = c * 2 + tc;
                Frag ahi[2], alo[2], bhi[2], blo[2];
                {   // A frags: lane holds A[m=ln(+32rt)][k = t*16 + l5*8 + j]
                    const int kg0 = t * 4 + l5 * 2;
                    const int sw0 = kg0 & 7, sw1 = (kg0 + 1) & 7;
                    #pragma unroll
                    for (int rt = 0; rt < 2; ++rt) {
                        const int m = rt * 32 + ln;
                        uint32_t w[8];
                        *(uint4*)&w[0] = *(const uint4*)&lds[(kg0 << 8) + ((m ^ sw0) << 2)];
                        *(uint4*)&w[4] = *(const uint4*)&lds[((kg0 + 1) << 8) + ((m ^ sw1) << 2)];
                        #pragma unroll
                        for (int i = 0; i < 4; ++i) {
                            ahi[rt].u[i] = __builtin_amdgcn_perm(w[2 * i + 1], w[2 * i], 0x05040100u);
                            alo[rt].u[i] = __builtin_amdgcn_perm(w[2 * i + 1], w[2 * i], 0x07060302u);
                        }
                    }
                }
                {   // B frags: lane holds W[k][n=wave*64+ct*32+ln]
                    const int kkg0 = tc * 4 + l5 * 2;
                    #pragma unroll
                    for (int ct = 0; ct < 2; ++ct) {
                        const int n = wave * 64 + ct * 32 + ln;
                        uint32_t w[8];
                        *(uint4*)&w[0] = *(const uint4*)&lds[bb0 + (kkg0 << 10) + (n << 2)];
                        *(uint4*)&w[4] = *(const uint4*)&lds[bb0 + ((kkg0 + 1) << 10) + (n << 2)];
                        #pragma unroll
                        for (int i = 0; i < 4; ++i) {
                            bhi[ct].u[i] = __builtin_amdgcn_perm(w[2 * i + 1], w[2 * i], 0x05040100u);
                            blo[ct].u[i] = __builtin_amdgcn_perm(w[2 * i + 1], w[2 * i], 0x07060302u);
                        }
                    }
                }
                #pragma unroll
                for (int rt = 0; rt < 2; ++rt)
                    #pragma unroll
                    for (int ct = 0; ct < 2; ++ct) {
                        acc[rt][ct] = __builtin_amdgcn_mfma_f32_32x32x16_bf16(ahi[rt].v, bhi[ct].v, acc[rt][ct], 0, 0, 0);
                        acc[rt][ct] = __builtin_amdgcn_mfma_f32_32x32x16_bf16(alo[rt].v, bhi[ct].v, acc[rt][ct], 0, 0, 0);
                        acc[rt][ct] = __builtin_amdgcn_mfma_f32_32x32x16_bf16(ahi[rt].v, blo[ct].v, acc[rt][ct], 0, 0, 0);
                    }
            }
            __syncthreads();
            p ^= 1;
        }

        if (l < 3) {
            // C layout: row = (reg&3) + 8*(reg>>2) + 4*(lane>>5), col = lane&31.
            // rows 4s..4s+3 = one sample's [h,d0,d1,d2] -> silu chain is lane-local.
            #pragma unroll
            for (int rt = 0; rt < 2; ++rt)
                #pragma unroll
                for (int ct = 0; ct < 2; ++ct) {
                    const int n  = wave * 64 + ct * 32 + ln;
                    const float bn = b_hid[l * 256 + n];
                    #pragma unroll
                    for (int rg = 0; rg < 4; ++rg) {
                        float pre = acc[rt][ct][rg * 4 + 0] + bn;
                        float sig = 1.f / (1.f + __expf(-pre));
                        float sp  = sig * (1.f + pre * (1.f - sig));
                        const int mb = rt * 32 + 8 * rg + 4 * l5;
                        lds[awords(mb + 0, n)] = pack_hilo(pre * sig);
                        lds[awords(mb + 1, n)] = pack_hilo(sp * acc[rt][ct][rg * 4 + 1]);
                        lds[awords(mb + 2, n)] = pack_hilo(sp * acc[rt][ct][rg * 4 + 2]);
                        lds[awords(mb + 3, n)] = pack_hilo(sp * acc[rt][ct][rg * 4 + 3]);
                    }
                }
            __syncthreads();
        } else {
            // dump raw output GEMM results (no bias) to E[s][state][n] fp32 (overlays sA)
            float* E = (float*)lds;
            #pragma unroll
            for (int rt = 0; rt < 2; ++rt)
                #pragma unroll
                for (int ct = 0; ct < 2; ++ct) {
                    const int n = wave * 64 + ct * 32 + ln;
                    #pragma unroll
                    for (int rg = 0; rg < 4; ++rg) {
                        const int smp = rt * 8 + 2 * rg + l5;
                        #pragma unroll
                        for (int st = 0; st < 4; ++st)
                            E[(smp * 4 + st) * 256 + n] = acc[rt][ct][rg * 4 + st];
                    }
                }
            __syncthreads();
            // final phase: lane = mixture (64), wave w -> samples 4w..4w+3
            const float4* E4 = (const float4*)lds;
            float4 bo = *(const float4*)&b_out[lane * 4];
            #pragma unroll
            for (int g = 0; g < 4; ++g) {
                const int sl = wave * 4 + g;
                float4 o  = E4[(sl * 4 + 0) * 64 + lane];
                float4 t1 = E4[(sl * 4 + 1) * 64 + lane];
                float4 t2 = E4[(sl * 4 + 2) * 64 + lane];
                float4 t3 = E4[(sl * 4 + 3) * 64 + lane];
                float sm  = o.x + bo.x;
                float oa0 = o.y + bo.y, oa1 = o.z + bo.z, oa2 = o.w + bo.w;
                float ds0 = t1.x, ds1 = t2.x, ds2 = t3.x;
                float mx = wmax(sm);
                float e  = __expf(sm - mx);
                float Z  = wsum(e);
                float T0 = wsum(e * ds0) / Z;
                float T1 = wsum(e * ds1) / Z;
                float T2 = wsum(e * ds2) / Z;
                float g0 =  (ds1 - T1) * oa0 + t2.y + (ds2 - T2) * oa1 + t3.z;
                float g1 = -((ds0 - T0) * oa0 + t1.y) + (ds2 - T2) * oa2 + t3.w;
                float g2 = -((ds0 - T0) * oa1 + t1.z) - ((ds1 - T1) * oa2 + t2.w);
                float u0 = wsum(e * g0) / Z;
                float u1 = wsum(e * g1) / Z;
                float u2 = wsum(e * g2) / Z;
                if (lane == 0) {
                    const int sg = s0 + sl;
                    out[sg * 3 + 0] = u0;
                    out[sg * 3 + 1] = u1;
                    out[sg * 3 + 2] = u2;
                }
            }
        }
    }
}

extern "C" void kernel_launch(void* const* d_in, const int* in_sizes, int n_in,
                              void* d_out, int out_size, void* d_ws, size_t ws_size,
                              hipStream_t stream) {
    const float* x     = (const float*)d_in[0];
    const float* w_in  = (const float*)d_in[1];
    const float* b_in  = (const float*)d_in[2];
    const float* w_hid = (const float*)d_in[3];
    const float* b_hid = (const float*)d_in[4];
    const float* w_out = (const float*)d_in[5];
    const float* b_out = (const float*)d_in[6];
    float* out = (float*)d_out;
    uint32_t* Wp = (uint32_t*)d_ws;                 // 1 MB packed-weight image
    const int N = in_sizes[0] / 3;

    pack_w<<<1024, 256, 0, stream>>>(w_hid, w_out, Wp);
    divfree_mfma<<<N / SPB, THREADS, 0, stream>>>(x, Wp, w_in, b_in, b_hid, b_out, out);
}

// Round 3
// 711.951 us; speedup vs baseline: 2.6540x; 1.0648x over previous
//
#include <hip/hip_runtime.h>
#include <stdint.h>

#define THREADS 512
#define SPB 32                 // samples per block -> 128 A-rows
#define CHUNK_WORDS 4096       // one K=16 chunk: hi plane 2048 + lo plane 2048 words
#define LAYER_WORDS 65536      // 16 chunks per 256x256 layer
#define SB_BASE 32768          // sA = 32768 words (128 KB)
// total LDS = 32768 + 2*4096 = 40960 words = 160 KB exactly

typedef __bf16 bf16x8 __attribute__((ext_vector_type(8)));
typedef float f32x16 __attribute__((ext_vector_type(16)));

union Frag { uint32_t u[4]; bf16x8 v; };

__device__ __forceinline__ uint32_t f2bf(float f) {    // RNE bf16 bits
    uint32_t u = __float_as_uint(f);
    return (u + 0x7fffu + ((u >> 16) & 1u)) >> 16;
}
__device__ __forceinline__ uint32_t pack_hilo(float f) {
    uint32_t hb = f2bf(f);
    float hf = __uint_as_float(hb << 16);
    uint32_t lb = f2bf(f - hf);
    return hb | (lb << 16);
}
// sA word address: granule slab kg=k>>2 (128 rows x 4 words), XOR-swizzled
__device__ __forceinline__ int awords(int m, int k) {
    int kg = k >> 2;
    return (kg << 9) + ((m ^ (kg & 7)) << 2) + (k & 3);
}
__device__ __forceinline__ float wsum(float v) {
    #pragma unroll
    for (int off = 32; off > 0; off >>= 1) v += __shfl_xor(v, off, 64);
    return v;
}
__device__ __forceinline__ float wmax(float v) {
    #pragma unroll
    for (int off = 32; off > 0; off >>= 1) v = fmaxf(v, __shfl_xor(v, off, 64));
    return v;
}

// ---- pre-kernel: pack W into planar hi/lo bf16 chunk images ----
// word idx = l*65536 + kt*4096 + plane*2048 + s8*1024 + n*4 + w
// holds bf16(k0)|bf16(k0+1)<<16 with k0 = kt*16 + s8*8 + 2w  (plane0=hi, plane1=lo)
__global__ __launch_bounds__(256) void pack_w(const float* __restrict__ w_hid,
                                              const float* __restrict__ w_out,
                                              uint32_t* __restrict__ Wp) {
    int idx = blockIdx.x * 256 + threadIdx.x;      // 0..262143
    int l     = idx >> 16;
    int r     = idx & 65535;
    int kt    = r >> 12;
    int r2    = r & 4095;
    int plane = r2 >> 11;
    int r3    = r2 & 2047;
    int s8    = r3 >> 10;
    int n     = (r3 >> 2) & 255;
    int w     = r3 & 3;
    int k0    = kt * 16 + s8 * 8 + 2 * w;
    const float* Wsrc = (l < 3) ? (w_hid + l * 65536) : w_out;
    float a = Wsrc[k0 * 256 + n];
    float b = Wsrc[(k0 + 1) * 256 + n];
    uint32_t ha = f2bf(a), hb = f2bf(b);
    uint32_t word;
    if (plane == 0) {
        word = ha | (hb << 16);
    } else {
        uint32_t la = f2bf(a - __uint_as_float(ha << 16));
        uint32_t lb = f2bf(b - __uint_as_float(hb << 16));
        word = la | (lb << 16);
    }
    Wp[idx] = word;
}

__global__ __launch_bounds__(THREADS) void divfree_mfma(
    const float* __restrict__ x,
    const uint32_t* __restrict__ Wp,
    const float* __restrict__ w_in,
    const float* __restrict__ b_in,
    const float* __restrict__ b_hid,
    const float* __restrict__ b_out,
    float* __restrict__ out)
{
    __shared__ uint32_t lds[40960];                // 160 KB
    const int tid  = threadIdx.x;
    const int wave = tid >> 6, lane = tid & 63;
    const int l5 = lane >> 5, ln = lane & 31;
    const int roww = wave & 1;                     // row-half of the 128x256 tile
    const int colw = wave >> 1;                    // 64-col strip
    const int s0 = blockIdx.x * SPB;

    auto stage = [&](const uint32_t* src, int bufbase) {
        const uint32_t* g = src + wave * 512 + lane * 4;
        #pragma unroll
        for (int i = 0; i < 2; ++i) {
            __builtin_amdgcn_global_load_lds(
                (const __attribute__((address_space(1))) uint32_t*)(g + i * 256),
                (__attribute__((address_space(3))) uint32_t*)(&lds[bufbase + wave * 512 + i * 256 + lane * 4]),
                16, 0, 0);
        }
    };

    // async-stage layer0 chunk0 while computing the input layer
    stage(Wp, SB_BASE);

    { // ---- input layer: thread owns row m=tid&127, granules kg = i*4 + tid>>7 ----
        const int m   = tid & 127;
        const int s   = m >> 2;
        const int row = m & 3;
        const float x0 = x[(s0 + s) * 3 + 0];
        const float x1 = x[(s0 + s) * 3 + 1];
        const float x2 = x[(s0 + s) * 3 + 2];
        #pragma unroll
        for (int i = 0; i < 16; ++i) {
            const int kg = i * 4 + (tid >> 7);
            const int k0 = kg * 4;
            float4 w0 = *(const float4*)&w_in[k0];
            float4 w1 = *(const float4*)&w_in[256 + k0];
            float4 w2 = *(const float4*)&w_in[512 + k0];
            float4 bb = *(const float4*)&b_in[k0];
            float W0[4] = {w0.x, w0.y, w0.z, w0.w};
            float W1[4] = {w1.x, w1.y, w1.z, w1.w};
            float W2[4] = {w2.x, w2.y, w2.z, w2.w};
            float BB[4] = {bb.x, bb.y, bb.z, bb.w};
            uint32_t g4[4];
            #pragma unroll
            for (int e = 0; e < 4; ++e) {
                float pre = x0 * W0[e] + x1 * W1[e] + x2 * W2[e] + BB[e];
                float sig = 1.f / (1.f + __expf(-pre));
                float sp  = sig * (1.f + pre * (1.f - sig));
                float wsel = (row == 1) ? W0[e] : (row == 2) ? W1[e] : W2[e];
                float val  = (row == 0) ? pre * sig : sp * wsel;
                g4[e] = pack_hilo(val);
            }
            *(uint4*)&lds[(kg << 9) + ((m ^ (kg & 7)) << 2)] = *(uint4*)g4;
        }
    }
    __syncthreads();

    int p = 0;
    #pragma unroll 1
    for (int l = 0; l < 4; ++l) {
        f32x16 acc[2][2];
        #pragma unroll
        for (int a = 0; a < 2; ++a)
            #pragma unroll
            for (int b = 0; b < 2; ++b) acc[a][b] = (f32x16)0.0f;

        #pragma unroll 1
        for (int c = 0; c < 16; ++c) {             // one K=16 t-step per chunk
            if (c < 15)      stage(Wp + l * LAYER_WORDS + (c + 1) * CHUNK_WORDS, SB_BASE + (p ^ 1) * CHUNK_WORDS);
            else if (l < 3)  stage(Wp + (l + 1) * LAYER_WORDS, SB_BASE + (p ^ 1) * CHUNK_WORDS);

            const int bb0 = SB_BASE + p * CHUNK_WORDS;
            Frag ahi[2], alo[2], bhi[2], blo[2];
            {   // A frags: lane holds A[m][k = c*16 + l5*8 + j], packed hi|lo
                const int kg0 = c * 4 + l5 * 2;
                const int sw0 = kg0 & 7, sw1 = (kg0 + 1) & 7;
                #pragma unroll
                for (int rt = 0; rt < 2; ++rt) {
                    const int m = roww * 64 + rt * 32 + ln;
                    uint32_t w[8];
                    *(uint4*)&w[0] = *(const uint4*)&lds[(kg0 << 9) + ((m ^ sw0) << 2)];
                    *(uint4*)&w[4] = *(const uint4*)&lds[((kg0 + 1) << 9) + ((m ^ sw1) << 2)];
                    #pragma unroll
                    for (int i = 0; i < 4; ++i) {
                        ahi[rt].u[i] = __builtin_amdgcn_perm(w[2 * i + 1], w[2 * i], 0x05040100u);
                        alo[rt].u[i] = __builtin_amdgcn_perm(w[2 * i + 1], w[2 * i], 0x07060302u);
                    }
                }
            }
            {   // B frags: planar, direct b128, no unpack
                #pragma unroll
                for (int ct = 0; ct < 2; ++ct) {
                    const int n = colw * 64 + ct * 32 + ln;
                    *(uint4*)&bhi[ct].u[0] = *(const uint4*)&lds[bb0 + l5 * 1024 + n * 4];
                    *(uint4*)&blo[ct].u[0] = *(const uint4*)&lds[bb0 + 2048 + l5 * 1024 + n * 4];
                }
            }
            #pragma unroll
            for (int rt = 0; rt < 2; ++rt)
                #pragma unroll
                for (int ct = 0; ct < 2; ++ct) {
                    acc[rt][ct] = __builtin_amdgcn_mfma_f32_32x32x16_bf16(ahi[rt].v, bhi[ct].v, acc[rt][ct], 0, 0, 0);
                    acc[rt][ct] = __builtin_amdgcn_mfma_f32_32x32x16_bf16(alo[rt].v, bhi[ct].v, acc[rt][ct], 0, 0, 0);
                    acc[rt][ct] = __builtin_amdgcn_mfma_f32_32x32x16_bf16(ahi[rt].v, blo[ct].v, acc[rt][ct], 0, 0, 0);
                }
            __syncthreads();
            p ^= 1;
        }

        if (l < 3) {
            // C layout: row=(reg&3)+8*(reg>>2)+4*l5 (+rt*32+roww*64), col=ln (+ct*32+colw*64)
            #pragma unroll
            for (int rt = 0; rt < 2; ++rt)
                #pragma unroll
                for (int ct = 0; ct < 2; ++ct) {
                    const int n  = colw * 64 + ct * 32 + ln;
                    const float bn = b_hid[l * 256 + n];
                    #pragma unroll
                    for (int rg = 0; rg < 4; ++rg) {
                        float pre = acc[rt][ct][rg * 4 + 0] + bn;
                        float sig = 1.f / (1.f + __expf(-pre));
                        float sp  = sig * (1.f + pre * (1.f - sig));
                        const int mb = roww * 64 + rt * 32 + 8 * rg + 4 * l5;
                        lds[awords(mb + 0, n)] = pack_hilo(pre * sig);
                        lds[awords(mb + 1, n)] = pack_hilo(sp * acc[rt][ct][rg * 4 + 1]);
                        lds[awords(mb + 2, n)] = pack_hilo(sp * acc[rt][ct][rg * 4 + 2]);
                        lds[awords(mb + 3, n)] = pack_hilo(sp * acc[rt][ct][rg * 4 + 3]);
                    }
                }
            __syncthreads();
        } else {
            // dump raw output-GEMM results to E[smp][state][n] fp32 (overlays sA)
            float* E = (float*)lds;
            #pragma unroll
            for (int rt = 0; rt < 2; ++rt)
                #pragma unroll
                for (int ct = 0; ct < 2; ++ct) {
                    const int n = colw * 64 + ct * 32 + ln;
                    #pragma unroll
                    for (int rg = 0; rg < 4; ++rg) {
                        const int smp = roww * 16 + rt * 8 + 2 * rg + l5;
                        #pragma unroll
                        for (int st = 0; st < 4; ++st)
                            E[(smp * 4 + st) * 256 + n] = acc[rt][ct][rg * 4 + st];
                    }
                }
            __syncthreads();
            // final phase: lane = mixture, wave w -> samples 4w..4w+3
            const float4* E4 = (const float4*)lds;
            float4 bo = *(const float4*)&b_out[lane * 4];
            #pragma unroll
            for (int g = 0; g < 4; ++g) {
                const int sl = wave * 4 + g;
                float4 o  = E4[(sl * 4 + 0) * 64 + lane];
                float4 t1 = E4[(sl * 4 + 1) * 64 + lane];
                float4 t2 = E4[(sl * 4 + 2) * 64 + lane];
                float4 t3 = E4[(sl * 4 + 3) * 64 + lane];
                float sm  = o.x + bo.x;
                float oa0 = o.y + bo.y, oa1 = o.z + bo.z, oa2 = o.w + bo.w;
                float ds0 = t1.x, ds1 = t2.x, ds2 = t3.x;
                float mx = wmax(sm);
                float e  = __expf(sm - mx);
                float Z  = wsum(e);
                float T0 = wsum(e * ds0) / Z;
                float T1 = wsum(e * ds1) / Z;
                float T2 = wsum(e * ds2) / Z;
                float g0 =  (ds1 - T1) * oa0 + t2.y + (ds2 - T2) * oa1 + t3.z;
                float g1 = -((ds0 - T0) * oa0 + t1.y) + (ds2 - T2) * oa2 + t3.w;
                float g2 = -((ds0 - T0) * oa1 + t1.z) - ((ds1 - T1) * oa2 + t2.w);
                float u0 = wsum(e * g0) / Z;
                float u1 = wsum(e * g1) / Z;
                float u2 = wsum(e * g2) / Z;
                if (lane == 0) {
                    const int sg = s0 + sl;
                    out[sg * 3 + 0] = u0;
                    out[sg * 3 + 1] = u1;
                    out[sg * 3 + 2] = u2;
                }
            }
        }
    }
}

extern "C" void kernel_launch(void* const* d_in, const int* in_sizes, int n_in,
                              void* d_out, int out_size, void* d_ws, size_t ws_size,
                              hipStream_t stream) {
    const float* x     = (const float*)d_in[0];
    const float* w_in  = (const float*)d_in[1];
    const float* b_in  = (const float*)d_in[2];
    const float* w_hid = (const float*)d_in[3];
    const float* b_hid = (const float*)d_in[4];
    const float* w_out = (const float*)d_in[5];
    const float* b_out = (const float*)d_in[6];
    float* out = (float*)d_out;
    uint32_t* Wp = (uint32_t*)d_ws;                 // 1 MB packed-weight image
    const int N = in_sizes[0] / 3;

    pack_w<<<1024, 256, 0, stream>>>(w_hid, w_out, Wp);
    divfree_mfma<<<N / SPB, THREADS, 0, stream>>>(x, Wp, w_in, b_in, b_hid, b_out, out);
}

// Round 4
// 579.095 us; speedup vs baseline: 3.2629x; 1.2294x over previous
//
#include <hip/hip_runtime.h>
#include <stdint.h>

#define THREADS 256
#define SPB 16                 // samples per block -> 64 A-rows
#define CHUNK_WORDS 4096       // one K=16 chunk: hi plane 2048 + lo plane 2048 words
#define NCHUNK_TOT 64          // 4 layers x 16 chunks, linearized

typedef __bf16 bf16x8 __attribute__((ext_vector_type(8)));
typedef float f32x16 __attribute__((ext_vector_type(16)));

union Frag { uint32_t u[4]; bf16x8 v; };

__device__ __forceinline__ uint32_t f2bf(float f) {    // RNE bf16 bits
    uint32_t u = __float_as_uint(f);
    return (u + 0x7fffu + ((u >> 16) & 1u)) >> 16;
}
__device__ __forceinline__ uint32_t pack_hilo(float f) {
    uint32_t hb = f2bf(f);
    float hf = __uint_as_float(hb << 16);
    uint32_t lb = f2bf(f - hf);
    return hb | (lb << 16);
}
// sA word address: granule slab kg=k>>2 (64 rows x 4 words), XOR-swizzled so both
// the epilogue writes (fixed m, varying kg) and frag reads (fixed kg, varying m)
// are conflict-free.
__device__ __forceinline__ int awords(int m, int k) {
    int kg = k >> 2;
    return (kg << 8) + ((m ^ (kg & 7)) << 2) + (k & 3);
}
__device__ __forceinline__ float wsum(float v) {
    #pragma unroll
    for (int off = 32; off > 0; off >>= 1) v += __shfl_xor(v, off, 64);
    return v;
}
__device__ __forceinline__ float wmax(float v) {
    #pragma unroll
    for (int off = 32; off > 0; off >>= 1) v = fmaxf(v, __shfl_xor(v, off, 64));
    return v;
}

// ---- pre-kernel: pack W into planar hi/lo bf16 chunk images ----
// word idx = l*65536 + kt*4096 + plane*2048 + s8*1024 + n*4 + w
// holds bf16(k0)|bf16(k0+1)<<16 with k0 = kt*16 + s8*8 + 2w  (plane0=hi, plane1=lo)
__global__ __launch_bounds__(256) void pack_w(const float* __restrict__ w_hid,
                                              const float* __restrict__ w_out,
                                              uint32_t* __restrict__ Wp) {
    int idx = blockIdx.x * 256 + threadIdx.x;      // 0..262143
    int l     = idx >> 16;
    int r     = idx & 65535;
    int kt    = r >> 12;
    int r2    = r & 4095;
    int plane = r2 >> 11;
    int r3    = r2 & 2047;
    int s8    = r3 >> 10;
    int n     = (r3 >> 2) & 255;
    int w     = r3 & 3;
    int k0    = kt * 16 + s8 * 8 + 2 * w;
    const float* Wsrc = (l < 3) ? (w_hid + l * 65536) : w_out;
    float a = Wsrc[k0 * 256 + n];
    float b = Wsrc[(k0 + 1) * 256 + n];
    uint32_t ha = f2bf(a), hb = f2bf(b);
    uint32_t word;
    if (plane == 0) {
        word = ha | (hb << 16);
    } else {
        uint32_t la = f2bf(a - __uint_as_float(ha << 16));
        uint32_t lb = f2bf(b - __uint_as_float(hb << 16));
        word = la | (lb << 16);
    }
    Wp[idx] = word;
}

__global__ __launch_bounds__(THREADS, 2) void divfree_mfma(
    const float* __restrict__ x,
    const uint32_t* __restrict__ Wp,
    const float* __restrict__ w_in,
    const float* __restrict__ b_in,
    const float* __restrict__ b_hid,
    const float* __restrict__ b_out,
    float* __restrict__ out)
{
    __shared__ uint32_t lds[16384];                // 64 KB: sA only -> 2 blocks/CU
    const int tid  = threadIdx.x;
    const int wave = tid >> 6, lane = tid & 63;
    const int l5 = lane >> 5, ln = lane & 31;
    const int s0 = blockIdx.x * SPB;

    // B-frag global addresses (per lane): hi plane word base for each ct
    const int n4[2] = { (wave * 64 + 0 * 32 + ln) * 4, (wave * 64 + 1 * 32 + ln) * 4 };

    // software-pipelined B prefetch (1 chunk ahead, linear chunk index 0..63)
    uint4 bh_n[2], bl_n[2];
    {
        const uint32_t* Bb = Wp + l5 * 1024;
        bh_n[0] = *(const uint4*)(Bb + n4[0]);
        bl_n[0] = *(const uint4*)(Bb + 2048 + n4[0]);
        bh_n[1] = *(const uint4*)(Bb + n4[1]);
        bl_n[1] = *(const uint4*)(Bb + 2048 + n4[1]);
    }

    { // ---- input layer: thread owns row m=tid&63, granules kg = i*4 + tid>>6 ----
        const int m   = tid & 63;
        const int s   = m >> 2;
        const int row = m & 3;
        const float x0 = x[(s0 + s) * 3 + 0];
        const float x1 = x[(s0 + s) * 3 + 1];
        const float x2 = x[(s0 + s) * 3 + 2];
        #pragma unroll
        for (int i = 0; i < 16; ++i) {
            const int kg = i * 4 + (tid >> 6);
            const int k0 = kg * 4;
            float4 w0 = *(const float4*)&w_in[k0];
            float4 w1 = *(const float4*)&w_in[256 + k0];
            float4 w2 = *(const float4*)&w_in[512 + k0];
            float4 bb = *(const float4*)&b_in[k0];
            float W0[4] = {w0.x, w0.y, w0.z, w0.w};
            float W1[4] = {w1.x, w1.y, w1.z, w1.w};
            float W2[4] = {w2.x, w2.y, w2.z, w2.w};
            float BB[4] = {bb.x, bb.y, bb.z, bb.w};
            uint32_t g4[4];
            #pragma unroll
            for (int e = 0; e < 4; ++e) {
                float pre = x0 * W0[e] + x1 * W1[e] + x2 * W2[e] + BB[e];
                float sig = 1.f / (1.f + __expf(-pre));
                float sp  = sig * (1.f + pre * (1.f - sig));
                float wsel = (row == 1) ? W0[e] : (row == 2) ? W1[e] : W2[e];
                float val  = (row == 0) ? pre * sig : sp * wsel;
                g4[e] = pack_hilo(val);
            }
            *(uint4*)&lds[(kg << 8) + ((m ^ (kg & 7)) << 2)] = *(uint4*)g4;
        }
    }
    __syncthreads();

    #pragma unroll 1
    for (int l = 0; l < 4; ++l) {
        f32x16 acc[2][2];
        #pragma unroll
        for (int a = 0; a < 2; ++a)
            #pragma unroll
            for (int b = 0; b < 2; ++b) acc[a][b] = (f32x16)0.0f;

        #pragma unroll 2
        for (int t = 0; t < 16; ++t) {             // K=16 per t-step, NO barriers
            // consume current B, prefetch next chunk (linear across layers)
            Frag bhi[2], blo[2];
            #pragma unroll
            for (int ct = 0; ct < 2; ++ct) {
                *(uint4*)&bhi[ct].u[0] = bh_n[ct];
                *(uint4*)&blo[ct].u[0] = bl_n[ct];
            }
            int g  = l * 16 + t;
            int gn = (g + 1 < NCHUNK_TOT) ? g + 1 : g;
            const uint32_t* Bb = Wp + gn * CHUNK_WORDS + l5 * 1024;
            #pragma unroll
            for (int ct = 0; ct < 2; ++ct) {
                bh_n[ct] = *(const uint4*)(Bb + n4[ct]);
                bl_n[ct] = *(const uint4*)(Bb + 2048 + n4[ct]);
            }

            // A frags from LDS: lane holds A[m][k = t*16 + l5*8 + j], packed hi|lo
            Frag ahi[2], alo[2];
            const int kg0 = t * 4 + l5 * 2;
            const int sw0 = kg0 & 7, sw1 = (kg0 + 1) & 7;
            #pragma unroll
            for (int rt = 0; rt < 2; ++rt) {
                const int m = rt * 32 + ln;
                uint32_t w[8];
                *(uint4*)&w[0] = *(const uint4*)&lds[(kg0 << 8) + ((m ^ sw0) << 2)];
                *(uint4*)&w[4] = *(const uint4*)&lds[((kg0 + 1) << 8) + ((m ^ sw1) << 2)];
                #pragma unroll
                for (int i = 0; i < 4; ++i) {
                    ahi[rt].u[i] = __builtin_amdgcn_perm(w[2 * i + 1], w[2 * i], 0x05040100u);
                    alo[rt].u[i] = __builtin_amdgcn_perm(w[2 * i + 1], w[2 * i], 0x07060302u);
                }
            }
            #pragma unroll
            for (int rt = 0; rt < 2; ++rt)
                #pragma unroll
                for (int ct = 0; ct < 2; ++ct) {
                    acc[rt][ct] = __builtin_amdgcn_mfma_f32_32x32x16_bf16(ahi[rt].v, bhi[ct].v, acc[rt][ct], 0, 0, 0);
                    acc[rt][ct] = __builtin_amdgcn_mfma_f32_32x32x16_bf16(alo[rt].v, bhi[ct].v, acc[rt][ct], 0, 0, 0);
                    acc[rt][ct] = __builtin_amdgcn_mfma_f32_32x32x16_bf16(ahi[rt].v, blo[ct].v, acc[rt][ct], 0, 0, 0);
                }
        }
        __syncthreads();                           // all waves done READING sA(l)

        if (l < 3) {
            // C layout: row = st + 8*rg + 4*l5 (+rt*32), col = ln (+ct*32+wave*64)
            #pragma unroll
            for (int rt = 0; rt < 2; ++rt)
                #pragma unroll
                for (int ct = 0; ct < 2; ++ct) {
                    const int n  = wave * 64 + ct * 32 + ln;
                    const float bn = b_hid[l * 256 + n];
                    #pragma unroll
                    for (int rg = 0; rg < 4; ++rg) {
                        float pre = acc[rt][ct][rg * 4 + 0] + bn;
                        float sig = 1.f / (1.f + __expf(-pre));
                        float sp  = sig * (1.f + pre * (1.f - sig));
                        const int mb = rt * 32 + 8 * rg + 4 * l5;
                        lds[awords(mb + 0, n)] = pack_hilo(pre * sig);
                        lds[awords(mb + 1, n)] = pack_hilo(sp * acc[rt][ct][rg * 4 + 1]);
                        lds[awords(mb + 2, n)] = pack_hilo(sp * acc[rt][ct][rg * 4 + 2]);
                        lds[awords(mb + 3, n)] = pack_hilo(sp * acc[rt][ct][rg * 4 + 3]);
                    }
                }
            __syncthreads();                       // sA(l+1) visible
        } else {
            // dump raw output-GEMM results to E[smp][state][n] fp32 (overlays sA)
            float* E = (float*)lds;
            #pragma unroll
            for (int rt = 0; rt < 2; ++rt)
                #pragma unroll
                for (int ct = 0; ct < 2; ++ct) {
                    const int n = wave * 64 + ct * 32 + ln;
                    #pragma unroll
                    for (int rg = 0; rg < 4; ++rg) {
                        const int smp = rt * 8 + 2 * rg + l5;
                        #pragma unroll
                        for (int st = 0; st < 4; ++st)
                            E[(smp * 4 + st) * 256 + n] = acc[rt][ct][rg * 4 + st];
                    }
                }
            __syncthreads();
            // final phase: lane = mixture, wave w -> samples 4w..4w+3
            const float4* E4 = (const float4*)lds;
            float4 bo = *(const float4*)&b_out[lane * 4];
            #pragma unroll
            for (int g = 0; g < 4; ++g) {
                const int sl = wave * 4 + g;
                float4 o  = E4[(sl * 4 + 0) * 64 + lane];
                float4 t1 = E4[(sl * 4 + 1) * 64 + lane];
                float4 t2 = E4[(sl * 4 + 2) * 64 + lane];
                float4 t3 = E4[(sl * 4 + 3) * 64 + lane];
                float sm  = o.x + bo.x;
                float oa0 = o.y + bo.y, oa1 = o.z + bo.z, oa2 = o.w + bo.w;
                float ds0 = t1.x, ds1 = t2.x, ds2 = t3.x;
                float mx = wmax(sm);
                float e  = __expf(sm - mx);
                float Z  = wsum(e);
                float T0 = wsum(e * ds0) / Z;
                float T1 = wsum(e * ds1) / Z;
                float T2 = wsum(e * ds2) / Z;
                float g0 =  (ds1 - T1) * oa0 + t2.y + (ds2 - T2) * oa1 + t3.z;
                float g1 = -((ds0 - T0) * oa0 + t1.y) + (ds2 - T2) * oa2 + t3.w;
                float g2 = -((ds0 - T0) * oa1 + t1.z) - ((ds1 - T1) * oa2 + t2.w);
                float u0 = wsum(e * g0) / Z;
                float u1 = wsum(e * g1) / Z;
                float u2 = wsum(e * g2) / Z;
                if (lane == 0) {
                    const int sg = s0 + sl;
                    out[sg * 3 + 0] = u0;
                    out[sg * 3 + 1] = u1;
                    out[sg * 3 + 2] = u2;
                }
            }
        }
    }
}

extern "C" void kernel_launch(void* const* d_in, const int* in_sizes, int n_in,
                              void* d_out, int out_size, void* d_ws, size_t ws_size,
                              hipStream_t stream) {
    const float* x     = (const float*)d_in[0];
    const float* w_in  = (const float*)d_in[1];
    const float* b_in  = (const float*)d_in[2];
    const float* w_hid = (const float*)d_in[3];
    const float* b_hid = (const float*)d_in[4];
    const float* w_out = (const float*)d_in[5];
    const float* b_out = (const float*)d_in[6];
    float* out = (float*)d_out;
    uint32_t* Wp = (uint32_t*)d_ws;                 // 1 MB packed-weight image
    const int N = in_sizes[0] / 3;

    pack_w<<<1024, 256, 0, stream>>>(w_hid, w_out, Wp);
    divfree_mfma<<<N / SPB, THREADS, 0, stream>>>(x, Wp, w_in, b_in, b_hid, b_out, out);
}

// Round 6
// 570.085 us; speedup vs baseline: 3.3145x; 1.0158x over previous
//
#include <hip/hip_runtime.h>
#include <stdint.h>

#define THREADS 512
#define SPB 16                 // samples per block -> 64 A-rows
#define CHUNK_WORDS 4096       // one K=16 chunk: hi plane 2048 + lo plane 2048 words
#define NCHUNK_TOT 64          // 4 layers x 16 chunks, linearized

typedef __bf16 bf16x8 __attribute__((ext_vector_type(8)));
typedef float f32x16 __attribute__((ext_vector_type(16)));

union Frag { uint32_t u[4]; bf16x8 v; };

__device__ __forceinline__ uint32_t f2bf(float f) {    // RNE bf16 bits
    uint32_t u = __float_as_uint(f);
    return (u + 0x7fffu + ((u >> 16) & 1u)) >> 16;
}
__device__ __forceinline__ uint32_t pack_hilo(float f) {
    uint32_t hb = f2bf(f);
    float hf = __uint_as_float(hb << 16);
    uint32_t lb = f2bf(f - hf);
    return hb | (lb << 16);
}
// sA word address: granule slab kg=k>>2 (64 rows x 4 words), XOR-swizzled so both
// epilogue writes (fixed m, varying kg) and frag reads (fixed kg, varying m) are
// conflict-free.  (R4-proven layout.)
__device__ __forceinline__ int awords(int m, int k) {
    int kg = k >> 2;
    return (kg << 8) + ((m ^ (kg & 7)) << 2) + (k & 3);
}
__device__ __forceinline__ float wsum(float v) {
    #pragma unroll
    for (int off = 32; off > 0; off >>= 1) v += __shfl_xor(v, off, 64);
    return v;
}
__device__ __forceinline__ float wmax(float v) {
    #pragma unroll
    for (int off = 32; off > 0; off >>= 1) v = fmaxf(v, __shfl_xor(v, off, 64));
    return v;
}

// ---- pre-kernel: pack W into planar hi/lo bf16 chunk images ----
// word idx = l*65536 + kt*4096 + plane*2048 + s8*1024 + n*4 + w
// holds bf16(k0)|bf16(k0+1)<<16 with k0 = kt*16 + s8*8 + 2w  (plane0=hi, plane1=lo)
__global__ __launch_bounds__(256) void pack_w(const float* __restrict__ w_hid,
                                              const float* __restrict__ w_out,
                                              uint32_t* __restrict__ Wp) {
    int idx = blockIdx.x * 256 + threadIdx.x;      // 0..262143
    int l     = idx >> 16;
    int r     = idx & 65535;
    int kt    = r >> 12;
    int r2    = r & 4095;
    int plane = r2 >> 11;
    int r3    = r2 & 2047;
    int s8    = r3 >> 10;
    int n     = (r3 >> 2) & 255;
    int w     = r3 & 3;
    int k0    = kt * 16 + s8 * 8 + 2 * w;
    const float* Wsrc = (l < 3) ? (w_hid + l * 65536) : w_out;
    float a = Wsrc[k0 * 256 + n];
    float b = Wsrc[(k0 + 1) * 256 + n];
    uint32_t ha = f2bf(a), hb = f2bf(b);
    uint32_t word;
    if (plane == 0) {
        word = ha | (hb << 16);
    } else {
        uint32_t la = f2bf(a - __uint_as_float(ha << 16));
        uint32_t lb = f2bf(b - __uint_as_float(hb << 16));
        word = la | (lb << 16);
    }
    Wp[idx] = word;
}

__global__ __launch_bounds__(THREADS, 4) void divfree_mfma(
    const float* __restrict__ x,
    const uint32_t* __restrict__ Wp,
    const float* __restrict__ w_in,
    const float* __restrict__ b_in,
    const float* __restrict__ b_hid,
    const float* __restrict__ b_out,
    float* __restrict__ out)
{
    __shared__ uint32_t lds[16384];                // 64 KB: sA only -> 2 blocks/CU
    const int tid  = threadIdx.x;
    const int wave = tid >> 6, lane = tid & 63;
    const int l5 = lane >> 5, ln = lane & 31;
    const int s0 = blockIdx.x * SPB;

    // B-frag global word offset (per lane): this wave's 32-col strip
    const int n4v = (wave * 32 + ln) * 4;

    // software-pipelined B prefetch (1 chunk ahead, linear chunk index 0..63)
    uint4 bh_n, bl_n;
    {
        const uint32_t* Bb = Wp + l5 * 1024;
        bh_n = *(const uint4*)(Bb + n4v);
        bl_n = *(const uint4*)(Bb + 2048 + n4v);
    }

    { // ---- input layer: thread owns row m=tid&63, granules kg = i*8 + tid>>6 ----
        const int m   = tid & 63;
        const int s   = m >> 2;
        const int row = m & 3;
        const float x0 = x[(s0 + s) * 3 + 0];
        const float x1 = x[(s0 + s) * 3 + 1];
        const float x2 = x[(s0 + s) * 3 + 2];
        #pragma unroll
        for (int i = 0; i < 8; ++i) {
            const int kg = i * 8 + (tid >> 6);
            const int k0 = kg * 4;
            float4 w0 = *(const float4*)&w_in[k0];
            float4 w1 = *(const float4*)&w_in[256 + k0];
            float4 w2 = *(const float4*)&w_in[512 + k0];
            float4 bb = *(const float4*)&b_in[k0];
            float W0[4] = {w0.x, w0.y, w0.z, w0.w};
            float W1[4] = {w1.x, w1.y, w1.z, w1.w};
            float W2[4] = {w2.x, w2.y, w2.z, w2.w};
            float BB[4] = {bb.x, bb.y, bb.z, bb.w};
            uint32_t g4[4];
            #pragma unroll
            for (int e = 0; e < 4; ++e) {
                float pre = x0 * W0[e] + x1 * W1[e] + x2 * W2[e] + BB[e];
                float sig = 1.f / (1.f + __expf(-pre));
                float sp  = sig * (1.f + pre * (1.f - sig));
                float wsel = (row == 1) ? W0[e] : (row == 2) ? W1[e] : W2[e];
                float val  = (row == 0) ? pre * sig : sp * wsel;
                g4[e] = pack_hilo(val);
            }
            *(uint4*)&lds[(kg << 8) + ((m ^ (kg & 7)) << 2)] = *(uint4*)g4;
        }
    }
    __syncthreads();

    #pragma unroll 1
    for (int l = 0; l < 4; ++l) {
        f32x16 acc[2];
        acc[0] = (f32x16)0.0f;
        acc[1] = (f32x16)0.0f;

        #pragma unroll 2
        for (int t = 0; t < 16; ++t) {             // K=16 per t-step, NO barriers
            // consume current B, prefetch next chunk (linear across layers)
            Frag bhi, blo;
            *(uint4*)&bhi.u[0] = bh_n;
            *(uint4*)&blo.u[0] = bl_n;
            int g  = l * 16 + t;
            int gn = (g + 1 < NCHUNK_TOT) ? g + 1 : g;
            const uint32_t* Bb = Wp + gn * CHUNK_WORDS + l5 * 1024;
            bh_n = *(const uint4*)(Bb + n4v);
            bl_n = *(const uint4*)(Bb + 2048 + n4v);

            // A frags from LDS: lane holds A[m=rt*32+ln][k = t*16 + l5*8 + j]
            Frag ahi[2], alo[2];
            const int kg0 = t * 4 + l5 * 2;
            const int sw0 = kg0 & 7, sw1 = (kg0 + 1) & 7;
            #pragma unroll
            for (int rt = 0; rt < 2; ++rt) {
                const int m = rt * 32 + ln;
                uint32_t w[8];
                *(uint4*)&w[0] = *(const uint4*)&lds[(kg0 << 8) + ((m ^ sw0) << 2)];
                *(uint4*)&w[4] = *(const uint4*)&lds[((kg0 + 1) << 8) + ((m ^ sw1) << 2)];
                #pragma unroll
                for (int i = 0; i < 4; ++i) {
                    ahi[rt].u[i] = __builtin_amdgcn_perm(w[2 * i + 1], w[2 * i], 0x05040100u);
                    alo[rt].u[i] = __builtin_amdgcn_perm(w[2 * i + 1], w[2 * i], 0x07060302u);
                }
            }
            #pragma unroll
            for (int rt = 0; rt < 2; ++rt) {
                acc[rt] = __builtin_amdgcn_mfma_f32_32x32x16_bf16(ahi[rt].v, bhi.v, acc[rt], 0, 0, 0);
                acc[rt] = __builtin_amdgcn_mfma_f32_32x32x16_bf16(alo[rt].v, bhi.v, acc[rt], 0, 0, 0);
                acc[rt] = __builtin_amdgcn_mfma_f32_32x32x16_bf16(ahi[rt].v, blo.v, acc[rt], 0, 0, 0);
            }
        }
        __syncthreads();                           // all waves done READING sA(l)

        if (l < 3) {
            // C layout: row = st + 8*rg + 4*l5 (+rt*32), col = n = wave*32+ln
            const int n  = wave * 32 + ln;
            const float bn = b_hid[l * 256 + n];
            #pragma unroll
            for (int rt = 0; rt < 2; ++rt) {
                #pragma unroll
                for (int rg = 0; rg < 4; ++rg) {
                    float pre = acc[rt][rg * 4 + 0] + bn;
                    float sig = 1.f / (1.f + __expf(-pre));
                    float sp  = sig * (1.f + pre * (1.f - sig));
                    const int mb = rt * 32 + 8 * rg + 4 * l5;
                    lds[awords(mb + 0, n)] = pack_hilo(pre * sig);
                    lds[awords(mb + 1, n)] = pack_hilo(sp * acc[rt][rg * 4 + 1]);
                    lds[awords(mb + 2, n)] = pack_hilo(sp * acc[rt][rg * 4 + 2]);
                    lds[awords(mb + 3, n)] = pack_hilo(sp * acc[rt][rg * 4 + 3]);
                }
            }
            __syncthreads();                       // sA(l+1) visible
        } else {
            // dump raw output-GEMM results to E[smp][state][n] fp32 (overlays sA)
            float* E = (float*)lds;
            const int n = wave * 32 + ln;
            #pragma unroll
            for (int rt = 0; rt < 2; ++rt) {
                #pragma unroll
                for (int rg = 0; rg < 4; ++rg) {
                    const int smp = rt * 8 + 2 * rg + l5;
                    #pragma unroll
                    for (int st = 0; st < 4; ++st)
                        E[(smp * 4 + st) * 256 + n] = acc[rt][rg * 4 + st];
                }
            }
            __syncthreads();
            // final phase: lane = mixture, wave w -> samples 2w..2w+1
            const float4* E4 = (const float4*)lds;
            float4 bo = *(const float4*)&b_out[lane * 4];
            #pragma unroll
            for (int g = 0; g < 2; ++g) {
                const int sl = wave * 2 + g;
                float4 o  = E4[(sl * 4 + 0) * 64 + lane];
                float4 t1 = E4[(sl * 4 + 1) * 64 + lane];
                float4 t2 = E4[(sl * 4 + 2) * 64 + lane];
                float4 t3 = E4[(sl * 4 + 3) * 64 + lane];
                float sm  = o.x + bo.x;
                float oa0 = o.y + bo.y, oa1 = o.z + bo.z, oa2 = o.w + bo.w;
                float ds0 = t1.x, ds1 = t2.x, ds2 = t3.x;
                float mx = wmax(sm);
                float e  = __expf(sm - mx);
                float Z  = wsum(e);
                float T0 = wsum(e * ds0) / Z;
                float T1 = wsum(e * ds1) / Z;
                float T2 = wsum(e * ds2) / Z;
                float g0 =  (ds1 - T1) * oa0 + t2.y + (ds2 - T2) * oa1 + t3.z;
                float g1 = -((ds0 - T0) * oa0 + t1.y) + (ds2 - T2) * oa2 + t3.w;
                float g2 = -((ds0 - T0) * oa1 + t1.z) - ((ds1 - T1) * oa2 + t2.w);
                float u0 = wsum(e * g0) / Z;
                float u1 = wsum(e * g1) / Z;
                float u2 = wsum(e * g2) / Z;
                if (lane == 0) {
                    const int sg = s0 + sl;
                    out[sg * 3 + 0] = u0;
                    out[sg * 3 + 1] = u1;
                    out[sg * 3 + 2] = u2;
                }
            }
        }
    }
}

extern "C" void kernel_launch(void* const* d_in, const int* in_sizes, int n_in,
                              void* d_out, int out_size, void* d_ws, size_t ws_size,
                              hipStream_t stream) {
    const float* x     = (const float*)d_in[0];
    const float* w_in  = (const float*)d_in[1];
    const float* b_in  = (const float*)d_in[2];
    const float* w_hid = (const float*)d_in[3];
    const float* b_hid = (const float*)d_in[4];
    const float* w_out = (const float*)d_in[5];
    const float* b_out = (const float*)d_in[6];
    float* out = (float*)d_out;
    uint32_t* Wp = (uint32_t*)d_ws;                 // 1 MB packed-weight image
    const int N = in_sizes[0] / 3;

    pack_w<<<1024, 256, 0, stream>>>(w_hid, w_out, Wp);
    divfree_mfma<<<N / SPB, THREADS, 0, stream>>>(x, Wp, w_in, b_in, b_hid, b_out, out);
}